// Round 4
// baseline (293.507 us; speedup 1.0000x reference)
//
#include <hip/hip_runtime.h>

#define BB 16
#define NN 2000
#define HH 720
#define WW 1280
#define NPT (BB*NN)           // 32000 keypoints
#define PT_BLOCKS (NPT/32)    // 1000 blocks, 4 waves x 8 points each
#define PPT 2                 // points per thread (knn)
#define NCHUNK 16             // chunk-lanes per point-group
#define CK (NN/NCHUNK)        // 125 m's per chunk-lane
#define KNN_PTS 32            // points per knn block
#define KNN_BLOCKS ((NN + KNN_PTS - 1) / KNN_PTS)   // 63 blocks per batch

static __device__ __forceinline__ unsigned u_min(unsigned a, unsigned b){ return a < b ? a : b; }
static __device__ __forceinline__ unsigned u_max(unsigned a, unsigned b){ return a > b ? a : b; }

// sorted top-5 insert (ascending uint keys), min/max network, 9 ops
__device__ __forceinline__ void ins5(unsigned K[5], unsigned u) {
    K[4] = u_min(K[4], u_max(K[3], u));
    K[3] = u_min(K[3], u_max(K[2], u));
    K[2] = u_min(K[2], u_max(K[1], u));
    K[1] = u_min(K[1], u_max(K[0], u));
    K[0] = u_min(K[0], u);
}

// ---------------- bilinear sample, exact reference semantics (fallback) -----
__device__ __forceinline__ float bilin(const float* __restrict__ im, float px, float py) {
    px = fminf(fmaxf(px, 0.f), (float)(WW - 1));
    py = fminf(fmaxf(py, 0.f), (float)(HH - 1));
    float x0f = floorf(px), y0f = floorf(py);
    float fx = px - x0f, fy = py - y0f;
    int x0 = min(max((int)x0f, 0), WW - 1);
    int x1 = min(x0 + 1, WW - 1);
    int y0 = min(max((int)y0f, 0), HH - 1);
    int y1 = min(y0 + 1, HH - 1);
    const float* r0 = im + (size_t)y0 * WW;
    const float* r1 = im + (size_t)y1 * WW;
    float v00 = r0[x0], v01 = r0[x1], v10 = r1[x0], v11 = r1[x1];
    return (v00 * (1.f - fx) + v01 * fx) * (1.f - fy)
         + (v10 * (1.f - fx) + v11 * fx) * fy;
}

// ---------------- Kernel A: patch loss + projection (unchanged, passing) ----
__global__ __launch_bounds__(256) void point_kernel(
    const float* __restrict__ lg, const float* __restrict__ rg,
    const float* __restrict__ kpl, const float* __restrict__ kpr,
    const float* __restrict__ scores, const float* __restrict__ Q,
    float4* __restrict__ pts, float* __restrict__ partials,
    float* __restrict__ batch_acc)
{
    if (blockIdx.x == 0 && threadIdx.x < BB * 4) batch_acc[threadIdx.x] = 0.f;

    int wave = threadIdx.x >> 6, lane = threadIdx.x & 63;
    int rr = lane / 7, ci = lane - rr * 7;      // sample (row,col) for lane<49
    int s00 = lane + rr;                        // = rr*8+ci in 8x8 region
    if (s00 > 54) s00 = 54;                     // keep shfl idx valid for lanes>=49
    int reg_r = lane >> 3, reg_c = lane & 7;    // region-load position

    float a0=0.f,a1=0.f,a2=0.f,a3=0.f,a4=0.f,a5=0.f,a6=0.f;

    for (int it = 0; it < 8; ++it) {
        int pt = blockIdx.x * 32 + wave * 8 + it;
        int b = pt / NN;
        const float* iml = lg + (size_t)b * (HH * WW);
        const float* imr = rg + (size_t)b * (HH * WW);
        float kxl = kpl[2*pt], kyl = kpl[2*pt+1];
        float kxr = kpr[2*pt], kyr = kpr[2*pt+1];
        float sc  = scores[pt];

        // ---- left patch ----
        float flx = floorf(kxl), fly = floorf(kyl);
        int xbl = (int)flx - 3, ybl = (int)fly - 3;
        float fxl = kxl - flx, fyl = kyl - fly;
        float vl = 0.f;
        if (xbl >= 0 && xbl <= WW-8 && ybl >= 0 && ybl <= HH-8) {  // wave-uniform
            float reg = iml[(size_t)(ybl + reg_r) * WW + xbl + reg_c];
            float v00 = __shfl(reg, s00,     64);
            float v01 = __shfl(reg, s00 + 1, 64);
            float v10 = __shfl(reg, s00 + 8, 64);
            float v11 = __shfl(reg, s00 + 9, 64);
            vl = (v00*(1.f-fxl) + v01*fxl)*(1.f-fyl) + (v10*(1.f-fxl) + v11*fxl)*fyl;
        } else if (lane < 49) {
            vl = bilin(iml, kxl + (float)(ci-3), kyl + (float)(rr-3));
        }
        // ---- right patch ----
        float frx = floorf(kxr), fry = floorf(kyr);
        int xbr = (int)frx - 3, ybr = (int)fry - 3;
        float fxr = kxr - frx, fyr = kyr - fry;
        float vr = 0.f;
        if (xbr >= 0 && xbr <= WW-8 && ybr >= 0 && ybr <= HH-8) {  // wave-uniform
            float reg = imr[(size_t)(ybr + reg_r) * WW + xbr + reg_c];
            float v00 = __shfl(reg, s00,     64);
            float v01 = __shfl(reg, s00 + 1, 64);
            float v10 = __shfl(reg, s00 + 8, 64);
            float v11 = __shfl(reg, s00 + 9, 64);
            vr = (v00*(1.f-fxr) + v01*fxr)*(1.f-fyr) + (v10*(1.f-fxr) + v11*fxr)*fyr;
        } else if (lane < 49) {
            vr = bilin(imr, kxr + (float)(ci-3), kyr + (float)(rr-3));
        }

        float adiff = (lane < 49) ? fabsf(vl - vr) : 0.f;
        float cl = __shfl(vl, 24, 64);   // center sample (3,3)
        float cr = __shfl(vr, 24, 64);
        #pragma unroll
        for (int off = 32; off > 0; off >>= 1) adiff += __shfl_down(adiff, off, 64);

        if (lane == 0) {
            float diff = adiff / 49.f;
            float isb  = (cl > 0.02f) ? 1.f : 0.f;   // BRIGHT
            float w    = sc * isb;
            float ydiff = fabsf(kyl - kyr);
            float dc = fabsf(cl - cr);
            float sl1 = (dc < 1.f) ? 0.5f * dc * dc : dc - 0.5f;

            const float* q = Q + b * 16;
            float dsp = kxl - kxr;
            float p0 = q[0]*kxl + q[1]*kyl + q[2]*dsp  + q[3];
            float p1 = q[4]*kxl + q[5]*kyl + q[6]*dsp  + q[7];
            float p2 = q[8]*kxl + q[9]*kyl + q[10]*dsp + q[11];
            float p3 = q[12]*kxl + q[13]*kyl + q[14]*dsp + q[15];
            float Wc = fmaxf(p3, 1e-6f);
            float X = p0 / Wc, Y = p1 / Wc, Z = p2 / Wc;
            bool valid = (Z > 100.f) && (Z < 30000.f) && (sc > 0.1f);
            float x  = X / 1000.f;
            float hh = Y / 1000.f;
            float y  = Z / 1000.f;
            float sq = x * x + y * y;
            if (!valid) { x = 0.f; y = 0.f; sq = 1e18f; }   // sentinel
            pts[pt] = make_float4(x, y, sq, hh);

            a0 += sc;  a1 += ydiff * sc;  a2 += ydiff;
            a3 += w;   a4 += diff * w;    a5 += sl1 * w;
            a6 += (sc > 0.1f) ? 1.f : 0.f;
        }
    }

    __shared__ float red[4][7];
    if (lane == 0) {
        red[wave][0]=a0; red[wave][1]=a1; red[wave][2]=a2; red[wave][3]=a3;
        red[wave][4]=a4; red[wave][5]=a5; red[wave][6]=a6;
    }
    __syncthreads();
    if (threadIdx.x < 8) {
        int k = threadIdx.x;
        float v = 0.f;
        if (k < 7) v = red[0][k] + red[1][k] + red[2][k] + red[3][k];
        partials[blockIdx.x * 8 + k] = v;
    }
}

// ---------------- Kernel B: KNN, 2 pts/thread, 32 pts/block, 4 waves/SIMD ---
// wave = 4 groups (g=lane>>4) x 16 chunks (c=lane&15); group owns 2 points.
// chunk c scans m in [c*125, (c+1)*125) with plain indexing (2-way banks = free).
__global__ __launch_bounds__(256) void knn_kernel(
    const float4* __restrict__ pts, float* __restrict__ batch_acc)
{
    __shared__ float4 tile[NN];   // 32 KB -> 5 blocks/CU LDS limit
    int b = blockIdx.y;
    for (int i = threadIdx.x; i < NN; i += 256) tile[i] = pts[b * NN + i];
    __syncthreads();

    int lane = threadIdx.x & 63, wave = threadIdx.x >> 6;
    int g = lane >> 4;            // group in wave (0..3)
    int c = lane & 15;            // chunk id (0..15)
    int n0 = blockIdx.x * KNN_PTS + (wave * 4 + g) * PPT;

    unsigned K[PPT][5];
    float nx2[PPT], ny2[PPT], sqn[PPT];
    bool act[PPT];
    #pragma unroll
    for (int j = 0; j < PPT; ++j) {
        int n = n0 + j;
        float4 me = (n < NN) ? tile[n] : make_float4(0.f, 0.f, 1e18f, 0.f);
        act[j] = (me.z < 1e17f);
        nx2[j] = -2.f * me.x; ny2[j] = -2.f * me.y; sqn[j] = me.z;
        #pragma unroll
        for (int t = 0; t < 5; ++t) K[j][t] = 0xFFFFFFFFu;
    }

    const int mbase = c * CK;
    #pragma unroll 5
    for (int mm = 0; mm < CK; ++mm) {
        int m = mbase + mm;
        float4 o = tile[m];
        #pragma unroll
        for (int j = 0; j < PPT; ++j) {
            float t = fmaf(ny2[j], o.y, o.z);
            t = fmaf(nx2[j], o.x, t);
            float d2 = fmaxf(t + sqn[j], 1e-12f);
            unsigned u = (__float_as_uint(d2) & 0xFFFFF800u) | (unsigned)m;
            u = (m == n0 + j) ? 0xFFFFFFFFu : u;   // exclude self in-loop
            ins5(K[j], u);
        }
    }

    // merge the 16 chunk lists of each group (xor offsets stay inside 16 lanes)
    #pragma unroll
    for (int off = 1; off < 16; off <<= 1) {
        #pragma unroll
        for (int j = 0; j < PPT; ++j) {
            unsigned B0 = (unsigned)__shfl_xor((int)K[j][0], off, 64);
            unsigned B1 = (unsigned)__shfl_xor((int)K[j][1], off, 64);
            unsigned B2 = (unsigned)__shfl_xor((int)K[j][2], off, 64);
            unsigned B3 = (unsigned)__shfl_xor((int)K[j][3], off, 64);
            unsigned B4 = (unsigned)__shfl_xor((int)K[j][4], off, 64);
            ins5(K[j], B0); ins5(K[j], B1); ins5(K[j], B2); ins5(K[j], B3); ins5(K[j], B4);
        }
    }

    float ls = 0.f, pen = 0.f, hacc = 0.f, cnt = 0.f;
    if (c == 0) {
        #pragma unroll
        for (int j = 0; j < PPT; ++j) {
            int n = n0 + j;
            if (n < NN && act[j]) {
                float4 me = tile[n];
                float hsum = 0.f;
                #pragma unroll
                for (int t = 0; t < 5; ++t) {
                    int idx = (int)(K[j][t] & 2047u);
                    float4 o = tile[idx];
                    float dot = me.x * o.x + me.y * o.y;
                    float d2 = (me.z + o.z) - 2.f * dot;        // exact recompute
                    float nd = fmaxf(sqrtf(fmaxf(d2, 1e-12f)), 0.001f);
                    hsum += o.w;
                    pen  += fmaxf(fabsf(o.w - me.w) / nd - 0.4f, 0.f);
                }
                float lm = hsum / 5.f;
                float dd = fabsf(me.w - lm);
                ls += (dd < 0.01f) ? 0.5f * dd * dd / 0.01f : dd - 0.005f;
                hacc += me.w;
                cnt  += 1.f;
            }
        }
    }
    // reduce active lanes {0,16,32,48} -> lane 0
    ls   += __shfl_down(ls,   32, 64);  pen  += __shfl_down(pen,  32, 64);
    hacc += __shfl_down(hacc, 32, 64);  cnt  += __shfl_down(cnt,  32, 64);
    ls   += __shfl_down(ls,   16, 64);  pen  += __shfl_down(pen,  16, 64);
    hacc += __shfl_down(hacc, 16, 64);  cnt  += __shfl_down(cnt,  16, 64);
    if (lane == 0) {
        atomicAdd(&batch_acc[b * 4 + 0], cnt);
        atomicAdd(&batch_acc[b * 4 + 1], ls);
        atomicAdd(&batch_acc[b * 4 + 2], pen);
        atomicAdd(&batch_acc[b * 4 + 3], hacc);
    }
}

// ---------------- Kernel C: final scalar epilogue ---------------------------
__global__ __launch_bounds__(256) void final_kernel(
    const float* __restrict__ partials, const float* __restrict__ batch_acc,
    float* __restrict__ out)
{
    float s[8] = {0,0,0,0,0,0,0,0};
    for (int r = threadIdx.x; r < PT_BLOCKS; r += 256) {
        #pragma unroll
        for (int k = 0; k < 8; ++k) s[k] += partials[r * 8 + k];
    }
    #pragma unroll
    for (int off = 32; off > 0; off >>= 1) {
        #pragma unroll
        for (int k = 0; k < 8; ++k) s[k] += __shfl_down(s[k], off, 64);
    }
    __shared__ float wsum_s[4][8];
    int wv = threadIdx.x >> 6, lane = threadIdx.x & 63;
    if (lane == 0) {
        #pragma unroll
        for (int k = 0; k < 8; ++k) wsum_s[wv][k] = s[k];
    }
    __syncthreads();
    if (threadIdx.x == 0) {
        float t[8];
        #pragma unroll
        for (int k = 0; k < 8; ++k)
            t[k] = wsum_s[0][k] + wsum_s[1][k] + wsum_s[2][k] + wsum_s[3][k];
        float ssc = t[0], yds = t[1], yd = t[2], wsum = t[3], dw = t[4], iw = t[5], cnts = t[6];

        float l_epi = (ssc > 1e-4f) ? yds / fmaxf(ssc, 1e-12f) : yd / (float)NPT;
        float safe = fmaxf(wsum, 1e-12f);
        float l_photo = (wsum > 1e-4f) ? (dw / safe + iw / safe) : 0.f;

        float als = 0.f, alsl = 0.f, alz = 0.f, okc = 0.f;
        for (int b = 0; b < BB; ++b) {
            float nvf  = batch_acc[b * 4 + 0];
            float lsb  = batch_acc[b * 4 + 1];
            float penb = batch_acc[b * 4 + 2];
            float hb   = batch_acc[b * 4 + 3];
            float nv = fmaxf(nvf, 1.f);
            float ok = (nvf >= 10.f) ? 1.f : 0.f;
            als  += ok * (lsb / nv);
            alsl += ok * (penb / (nv * 5.f));   // K = 5
            alz  += ok * fabsf(hb / nv);
            okc  += ok;
        }
        float nb = fmaxf(okc, 1.f);
        bool gate = (cnts >= 10.f) && (okc > 0.f);
        out[0] = l_photo;
        out[1] = l_epi;
        out[2] = gate ? als / nb : 0.f;
        out[3] = gate ? alsl / nb : 0.f;
        out[4] = gate ? alz / nb : 0.f;
    }
}

extern "C" void kernel_launch(void* const* d_in, const int* in_sizes, int n_in,
                              void* d_out, int out_size, void* d_ws, size_t ws_size,
                              hipStream_t stream)
{
    const float* lg     = (const float*)d_in[0];
    const float* rg     = (const float*)d_in[1];
    const float* kpl    = (const float*)d_in[2];
    const float* kpr    = (const float*)d_in[3];
    const float* scores = (const float*)d_in[4];
    const float* Q      = (const float*)d_in[5];
    float* out = (float*)d_out;

    char* ws = (char*)d_ws;
    float4* pts       = (float4*)ws;                  // 512000 B
    float*  partials  = (float*)(ws + 512000);        // 1000*8*4 = 32000 B
    float*  batch_acc = (float*)(ws + 544000);        // 16*4*4 = 256 B

    point_kernel<<<PT_BLOCKS, 256, 0, stream>>>(lg, rg, kpl, kpr, scores, Q,
                                                pts, partials, batch_acc);
    knn_kernel<<<dim3(KNN_BLOCKS, BB), 256, 0, stream>>>(pts, batch_acc);
    final_kernel<<<1, 256, 0, stream>>>(partials, batch_acc, out);
}

// Round 5
// 224.941 us; speedup vs baseline: 1.3048x; 1.3048x over previous
//
#include <hip/hip_runtime.h>

#define BB 16
#define NN 2000
#define HH 720
#define WW 1280
#define NPT (BB*NN)           // 32000 keypoints
#define PT_BLOCKS (NPT/32)    // 1000 blocks, 4 waves x 8 points each
#define PPT 4                 // points per thread (knn) — R3-proven
#define NCHUNK 16             // chunk-lanes per point-quad
#define CK (NN/NCHUNK)        // 125 m's per chunk-lane
#define KNN_BLOCKS ((NN + 63) / 64)   // 32 blocks of 64 points per batch

static __device__ __forceinline__ unsigned u_min(unsigned a, unsigned b){ return a < b ? a : b; }
static __device__ __forceinline__ unsigned u_max(unsigned a, unsigned b){ return a > b ? a : b; }

// sorted top-5 insert (ascending uint keys), min/max network, 9 ops, ILP 5
__device__ __forceinline__ void ins5(unsigned K[5], unsigned u) {
    K[4] = u_min(K[4], u_max(K[3], u));
    K[3] = u_min(K[3], u_max(K[2], u));
    K[2] = u_min(K[2], u_max(K[1], u));
    K[1] = u_min(K[1], u_max(K[0], u));
    K[0] = u_min(K[0], u);
}

// ---------------- bilinear sample, exact reference semantics (fallback) -----
__device__ __forceinline__ float bilin(const float* __restrict__ im, float px, float py) {
    px = fminf(fmaxf(px, 0.f), (float)(WW - 1));
    py = fminf(fmaxf(py, 0.f), (float)(HH - 1));
    float x0f = floorf(px), y0f = floorf(py);
    float fx = px - x0f, fy = py - y0f;
    int x0 = min(max((int)x0f, 0), WW - 1);
    int x1 = min(x0 + 1, WW - 1);
    int y0 = min(max((int)y0f, 0), HH - 1);
    int y1 = min(y0 + 1, HH - 1);
    const float* r0 = im + (size_t)y0 * WW;
    const float* r1 = im + (size_t)y1 * WW;
    float v00 = r0[x0], v01 = r0[x1], v10 = r1[x0], v11 = r1[x1];
    return (v00 * (1.f - fx) + v01 * fx) * (1.f - fy)
         + (v10 * (1.f - fx) + v11 * fx) * fy;
}

// ---------------- Kernel A: patch loss + projection (unchanged, passing) ----
__global__ __launch_bounds__(256) void point_kernel(
    const float* __restrict__ lg, const float* __restrict__ rg,
    const float* __restrict__ kpl, const float* __restrict__ kpr,
    const float* __restrict__ scores, const float* __restrict__ Q,
    float4* __restrict__ pts, float* __restrict__ partials,
    float* __restrict__ batch_acc)
{
    if (blockIdx.x == 0 && threadIdx.x < BB * 4) batch_acc[threadIdx.x] = 0.f;

    int wave = threadIdx.x >> 6, lane = threadIdx.x & 63;
    int rr = lane / 7, ci = lane - rr * 7;      // sample (row,col) for lane<49
    int s00 = lane + rr;                        // = rr*8+ci in 8x8 region
    if (s00 > 54) s00 = 54;                     // keep shfl idx valid for lanes>=49
    int reg_r = lane >> 3, reg_c = lane & 7;    // region-load position

    float a0=0.f,a1=0.f,a2=0.f,a3=0.f,a4=0.f,a5=0.f,a6=0.f;

    for (int it = 0; it < 8; ++it) {
        int pt = blockIdx.x * 32 + wave * 8 + it;
        int b = pt / NN;
        const float* iml = lg + (size_t)b * (HH * WW);
        const float* imr = rg + (size_t)b * (HH * WW);
        float kxl = kpl[2*pt], kyl = kpl[2*pt+1];
        float kxr = kpr[2*pt], kyr = kpr[2*pt+1];
        float sc  = scores[pt];

        // ---- left patch ----
        float flx = floorf(kxl), fly = floorf(kyl);
        int xbl = (int)flx - 3, ybl = (int)fly - 3;
        float fxl = kxl - flx, fyl = kyl - fly;
        float vl = 0.f;
        if (xbl >= 0 && xbl <= WW-8 && ybl >= 0 && ybl <= HH-8) {  // wave-uniform
            float reg = iml[(size_t)(ybl + reg_r) * WW + xbl + reg_c];
            float v00 = __shfl(reg, s00,     64);
            float v01 = __shfl(reg, s00 + 1, 64);
            float v10 = __shfl(reg, s00 + 8, 64);
            float v11 = __shfl(reg, s00 + 9, 64);
            vl = (v00*(1.f-fxl) + v01*fxl)*(1.f-fyl) + (v10*(1.f-fxl) + v11*fxl)*fyl;
        } else if (lane < 49) {
            vl = bilin(iml, kxl + (float)(ci-3), kyl + (float)(rr-3));
        }
        // ---- right patch ----
        float frx = floorf(kxr), fry = floorf(kyr);
        int xbr = (int)frx - 3, ybr = (int)fry - 3;
        float fxr = kxr - frx, fyr = kyr - fry;
        float vr = 0.f;
        if (xbr >= 0 && xbr <= WW-8 && ybr >= 0 && ybr <= HH-8) {  // wave-uniform
            float reg = imr[(size_t)(ybr + reg_r) * WW + xbr + reg_c];
            float v00 = __shfl(reg, s00,     64);
            float v01 = __shfl(reg, s00 + 1, 64);
            float v10 = __shfl(reg, s00 + 8, 64);
            float v11 = __shfl(reg, s00 + 9, 64);
            vr = (v00*(1.f-fxr) + v01*fxr)*(1.f-fyr) + (v10*(1.f-fxr) + v11*fxr)*fyr;
        } else if (lane < 49) {
            vr = bilin(imr, kxr + (float)(ci-3), kyr + (float)(rr-3));
        }

        float adiff = (lane < 49) ? fabsf(vl - vr) : 0.f;
        float cl = __shfl(vl, 24, 64);   // center sample (3,3)
        float cr = __shfl(vr, 24, 64);
        #pragma unroll
        for (int off = 32; off > 0; off >>= 1) adiff += __shfl_down(adiff, off, 64);

        if (lane == 0) {
            float diff = adiff / 49.f;
            float isb  = (cl > 0.02f) ? 1.f : 0.f;   // BRIGHT
            float w    = sc * isb;
            float ydiff = fabsf(kyl - kyr);
            float dc = fabsf(cl - cr);
            float sl1 = (dc < 1.f) ? 0.5f * dc * dc : dc - 0.5f;

            const float* q = Q + b * 16;
            float dsp = kxl - kxr;
            float p0 = q[0]*kxl + q[1]*kyl + q[2]*dsp  + q[3];
            float p1 = q[4]*kxl + q[5]*kyl + q[6]*dsp  + q[7];
            float p2 = q[8]*kxl + q[9]*kyl + q[10]*dsp + q[11];
            float p3 = q[12]*kxl + q[13]*kyl + q[14]*dsp + q[15];
            float Wc = fmaxf(p3, 1e-6f);
            float X = p0 / Wc, Y = p1 / Wc, Z = p2 / Wc;
            bool valid = (Z > 100.f) && (Z < 30000.f) && (sc > 0.1f);
            float x  = X / 1000.f;
            float hh = Y / 1000.f;
            float y  = Z / 1000.f;
            float sq = x * x + y * y;
            if (!valid) { x = 0.f; y = 0.f; sq = 1e18f; }   // sentinel
            pts[pt] = make_float4(x, y, sq, hh);

            a0 += sc;  a1 += ydiff * sc;  a2 += ydiff;
            a3 += w;   a4 += diff * w;    a5 += sl1 * w;
            a6 += (sc > 0.1f) ? 1.f : 0.f;
        }
    }

    __shared__ float red[4][7];
    if (lane == 0) {
        red[wave][0]=a0; red[wave][1]=a1; red[wave][2]=a2; red[wave][3]=a3;
        red[wave][4]=a4; red[wave][5]=a5; red[wave][6]=a6;
    }
    __syncthreads();
    if (threadIdx.x < 8) {
        int k = threadIdx.x;
        float v = 0.f;
        if (k < 7) v = red[0][k] + red[1][k] + red[2][k] + red[3][k];
        partials[blockIdx.x * 8 + k] = v;
    }
}

// ---------------- Kernel B: KNN, 4 pts/thread (R3 shape), non-carried stagger
// block = 256 threads = 4 waves; wave = 4 quads (qi=lane>>4) x 16 chunks (c=lane&15)
// quad owns 4 consecutive points; chunk c scans m in [c*125, (c+1)*125)
// stagger s=4*(c&1) breaks the 16-addr bank pattern to 2-way (free), computed
// per-iteration from mm (NOT loop-carried) so unroll-5 loads batch.
__global__ __launch_bounds__(256) void knn_kernel(
    const float4* __restrict__ pts, float* __restrict__ batch_acc)
{
    __shared__ float4 tile[NN];   // 32 KB
    int b = blockIdx.y;
    for (int i = threadIdx.x; i < NN; i += 256) tile[i] = pts[b * NN + i];
    __syncthreads();

    int lane = threadIdx.x & 63, wave = threadIdx.x >> 6;
    int qi = lane >> 4;           // quad in wave (0..3)
    int c  = lane & 15;           // chunk id (0..15)
    int n0 = blockIdx.x * 64 + (wave * 4 + qi) * PPT;

    unsigned K[PPT][5];
    float nx2[PPT], ny2[PPT], sqn[PPT];
    bool act[PPT];
    #pragma unroll
    for (int j = 0; j < PPT; ++j) {
        int n = n0 + j;
        float4 me = (n < NN) ? tile[n] : make_float4(0.f, 0.f, 1e18f, 0.f);
        act[j] = (me.z < 1e17f);
        nx2[j] = -2.f * me.x; ny2[j] = -2.f * me.y; sqn[j] = me.z;
        #pragma unroll
        for (int t = 0; t < 5; ++t) K[j][t] = 0xFFFFFFFFu;
    }

    const int mbase = c * CK;
    const int s = (c & 1) * 4;    // loop-invariant bank stagger
    #pragma unroll 5
    for (int mm = 0; mm < CK; ++mm) {
        int mm2 = mm + s;
        if (mm2 >= CK) mm2 -= CK;           // not loop-carried: direct fn of mm
        int m = mbase + mm2;
        float4 o = tile[m];
        #pragma unroll
        for (int j = 0; j < PPT; ++j) {
            float t = fmaf(ny2[j], o.y, o.z);
            t = fmaf(nx2[j], o.x, t);
            float d2 = fmaxf(t + sqn[j], 1e-12f);
            unsigned u = (__float_as_uint(d2) & 0xFFFFF800u) | (unsigned)m;
            u = (m == n0 + j) ? 0xFFFFFFFFu : u;   // exclude self in-loop
            ins5(K[j], u);
        }
    }

    // merge the 16 chunk lists of each quad (xor offsets stay in the 16-lane group)
    #pragma unroll
    for (int off = 1; off < 16; off <<= 1) {
        #pragma unroll
        for (int j = 0; j < PPT; ++j) {
            unsigned B0 = (unsigned)__shfl_xor((int)K[j][0], off, 64);
            unsigned B1 = (unsigned)__shfl_xor((int)K[j][1], off, 64);
            unsigned B2 = (unsigned)__shfl_xor((int)K[j][2], off, 64);
            unsigned B3 = (unsigned)__shfl_xor((int)K[j][3], off, 64);
            unsigned B4 = (unsigned)__shfl_xor((int)K[j][4], off, 64);
            ins5(K[j], B0); ins5(K[j], B1); ins5(K[j], B2); ins5(K[j], B3); ins5(K[j], B4);
        }
    }

    float ls = 0.f, pen = 0.f, hacc = 0.f, cnt = 0.f;
    if (c == 0) {
        #pragma unroll
        for (int j = 0; j < PPT; ++j) {
            int n = n0 + j;
            if (n < NN && act[j]) {
                float4 me = tile[n];
                float hsum = 0.f;
                #pragma unroll
                for (int t = 0; t < 5; ++t) {
                    int idx = (int)(K[j][t] & 2047u);
                    float4 o = tile[idx];
                    float dot = me.x * o.x + me.y * o.y;
                    float d2 = (me.z + o.z) - 2.f * dot;        // exact recompute
                    float nd = fmaxf(sqrtf(fmaxf(d2, 1e-12f)), 0.001f);
                    hsum += o.w;
                    pen  += fmaxf(fabsf(o.w - me.w) / nd - 0.4f, 0.f);
                }
                float lm = hsum / 5.f;
                float dd = fabsf(me.w - lm);
                ls += (dd < 0.01f) ? 0.5f * dd * dd / 0.01f : dd - 0.005f;
                hacc += me.w;
                cnt  += 1.f;
            }
        }
    }
    // reduce active lanes {0,16,32,48} -> lane 0
    ls   += __shfl_down(ls,   32, 64);  pen  += __shfl_down(pen,  32, 64);
    hacc += __shfl_down(hacc, 32, 64);  cnt  += __shfl_down(cnt,  32, 64);
    ls   += __shfl_down(ls,   16, 64);  pen  += __shfl_down(pen,  16, 64);
    hacc += __shfl_down(hacc, 16, 64);  cnt  += __shfl_down(cnt,  16, 64);
    if (lane == 0) {
        atomicAdd(&batch_acc[b * 4 + 0], cnt);
        atomicAdd(&batch_acc[b * 4 + 1], ls);
        atomicAdd(&batch_acc[b * 4 + 2], pen);
        atomicAdd(&batch_acc[b * 4 + 3], hacc);
    }
}

// ---------------- Kernel C: final scalar epilogue ---------------------------
__global__ __launch_bounds__(256) void final_kernel(
    const float* __restrict__ partials, const float* __restrict__ batch_acc,
    float* __restrict__ out)
{
    float s[8] = {0,0,0,0,0,0,0,0};
    for (int r = threadIdx.x; r < PT_BLOCKS; r += 256) {
        #pragma unroll
        for (int k = 0; k < 8; ++k) s[k] += partials[r * 8 + k];
    }
    #pragma unroll
    for (int off = 32; off > 0; off >>= 1) {
        #pragma unroll
        for (int k = 0; k < 8; ++k) s[k] += __shfl_down(s[k], off, 64);
    }
    __shared__ float wsum_s[4][8];
    int wv = threadIdx.x >> 6, lane = threadIdx.x & 63;
    if (lane == 0) {
        #pragma unroll
        for (int k = 0; k < 8; ++k) wsum_s[wv][k] = s[k];
    }
    __syncthreads();
    if (threadIdx.x == 0) {
        float t[8];
        #pragma unroll
        for (int k = 0; k < 8; ++k)
            t[k] = wsum_s[0][k] + wsum_s[1][k] + wsum_s[2][k] + wsum_s[3][k];
        float ssc = t[0], yds = t[1], yd = t[2], wsum = t[3], dw = t[4], iw = t[5], cnts = t[6];

        float l_epi = (ssc > 1e-4f) ? yds / fmaxf(ssc, 1e-12f) : yd / (float)NPT;
        float safe = fmaxf(wsum, 1e-12f);
        float l_photo = (wsum > 1e-4f) ? (dw / safe + iw / safe) : 0.f;

        float als = 0.f, alsl = 0.f, alz = 0.f, okc = 0.f;
        for (int b = 0; b < BB; ++b) {
            float nvf  = batch_acc[b * 4 + 0];
            float lsb  = batch_acc[b * 4 + 1];
            float penb = batch_acc[b * 4 + 2];
            float hb   = batch_acc[b * 4 + 3];
            float nv = fmaxf(nvf, 1.f);
            float ok = (nvf >= 10.f) ? 1.f : 0.f;
            als  += ok * (lsb / nv);
            alsl += ok * (penb / (nv * 5.f));   // K = 5
            alz  += ok * fabsf(hb / nv);
            okc  += ok;
        }
        float nb = fmaxf(okc, 1.f);
        bool gate = (cnts >= 10.f) && (okc > 0.f);
        out[0] = l_photo;
        out[1] = l_epi;
        out[2] = gate ? als / nb : 0.f;
        out[3] = gate ? alsl / nb : 0.f;
        out[4] = gate ? alz / nb : 0.f;
    }
}

extern "C" void kernel_launch(void* const* d_in, const int* in_sizes, int n_in,
                              void* d_out, int out_size, void* d_ws, size_t ws_size,
                              hipStream_t stream)
{
    const float* lg     = (const float*)d_in[0];
    const float* rg     = (const float*)d_in[1];
    const float* kpl    = (const float*)d_in[2];
    const float* kpr    = (const float*)d_in[3];
    const float* scores = (const float*)d_in[4];
    const float* Q      = (const float*)d_in[5];
    float* out = (float*)d_out;

    char* ws = (char*)d_ws;
    float4* pts       = (float4*)ws;                  // 512000 B
    float*  partials  = (float*)(ws + 512000);        // 1000*8*4 = 32000 B
    float*  batch_acc = (float*)(ws + 544000);        // 16*4*4 = 256 B

    point_kernel<<<PT_BLOCKS, 256, 0, stream>>>(lg, rg, kpl, kpr, scores, Q,
                                                pts, partials, batch_acc);
    knn_kernel<<<dim3(KNN_BLOCKS, BB), 256, 0, stream>>>(pts, batch_acc);
    final_kernel<<<1, 256, 0, stream>>>(partials, batch_acc, out);
}

// Round 6
// 210.476 us; speedup vs baseline: 1.3945x; 1.0687x over previous
//
#include <hip/hip_runtime.h>

#define BB 16
#define NN 2000
#define HH 720
#define WW 1280
#define NPT (BB*NN)           // 32000 keypoints
#define PT_BLOCKS (NPT/32)    // 1000 blocks, 4 waves x 8 points each
#define PPT 4                 // points per thread (knn scan) — R3-proven shape
#define NCHUNK 16             // chunk-lanes per point-quad
#define NSPLIT 5              // m-range splits
#define MSEG (NN/NSPLIT)      // 400 candidates per segment
#define CK2 (MSEG/NCHUNK)     // 25 m's per chunk-lane
#define KSTRIDE 2048          // keybuf point stride (>= 32*64)

static __device__ __forceinline__ unsigned u_min(unsigned a, unsigned b){ return a < b ? a : b; }
static __device__ __forceinline__ unsigned u_max(unsigned a, unsigned b){ return a > b ? a : b; }

// sorted top-5 insert (ascending uint keys), min/max network, 9 ops
__device__ __forceinline__ void ins5(unsigned K[5], unsigned u) {
    K[4] = u_min(K[4], u_max(K[3], u));
    K[3] = u_min(K[3], u_max(K[2], u));
    K[2] = u_min(K[2], u_max(K[1], u));
    K[1] = u_min(K[1], u_max(K[0], u));
    K[0] = u_min(K[0], u);
}

// ---------------- bilinear sample, exact reference semantics (fallback) -----
__device__ __forceinline__ float bilin(const float* __restrict__ im, float px, float py) {
    px = fminf(fmaxf(px, 0.f), (float)(WW - 1));
    py = fminf(fmaxf(py, 0.f), (float)(HH - 1));
    float x0f = floorf(px), y0f = floorf(py);
    float fx = px - x0f, fy = py - y0f;
    int x0 = min(max((int)x0f, 0), WW - 1);
    int x1 = min(x0 + 1, WW - 1);
    int y0 = min(max((int)y0f, 0), HH - 1);
    int y1 = min(y0 + 1, HH - 1);
    const float* r0 = im + (size_t)y0 * WW;
    const float* r1 = im + (size_t)y1 * WW;
    float v00 = r0[x0], v01 = r0[x1], v10 = r1[x0], v11 = r1[x1];
    return (v00 * (1.f - fx) + v01 * fx) * (1.f - fy)
         + (v10 * (1.f - fx) + v11 * fx) * fy;
}

// ---------------- Kernel A: patch loss + projection (unchanged, passing) ----
__global__ __launch_bounds__(256) void point_kernel(
    const float* __restrict__ lg, const float* __restrict__ rg,
    const float* __restrict__ kpl, const float* __restrict__ kpr,
    const float* __restrict__ scores, const float* __restrict__ Q,
    float4* __restrict__ pts, float* __restrict__ partials,
    float* __restrict__ batch_acc)
{
    if (blockIdx.x == 0 && threadIdx.x < BB * 4) batch_acc[threadIdx.x] = 0.f;

    int wave = threadIdx.x >> 6, lane = threadIdx.x & 63;
    int rr = lane / 7, ci = lane - rr * 7;      // sample (row,col) for lane<49
    int s00 = lane + rr;                        // = rr*8+ci in 8x8 region
    if (s00 > 54) s00 = 54;                     // keep shfl idx valid for lanes>=49
    int reg_r = lane >> 3, reg_c = lane & 7;    // region-load position

    float a0=0.f,a1=0.f,a2=0.f,a3=0.f,a4=0.f,a5=0.f,a6=0.f;

    for (int it = 0; it < 8; ++it) {
        int pt = blockIdx.x * 32 + wave * 8 + it;
        int b = pt / NN;
        const float* iml = lg + (size_t)b * (HH * WW);
        const float* imr = rg + (size_t)b * (HH * WW);
        float kxl = kpl[2*pt], kyl = kpl[2*pt+1];
        float kxr = kpr[2*pt], kyr = kpr[2*pt+1];
        float sc  = scores[pt];

        // ---- left patch ----
        float flx = floorf(kxl), fly = floorf(kyl);
        int xbl = (int)flx - 3, ybl = (int)fly - 3;
        float fxl = kxl - flx, fyl = kyl - fly;
        float vl = 0.f;
        if (xbl >= 0 && xbl <= WW-8 && ybl >= 0 && ybl <= HH-8) {  // wave-uniform
            float reg = iml[(size_t)(ybl + reg_r) * WW + xbl + reg_c];
            float v00 = __shfl(reg, s00,     64);
            float v01 = __shfl(reg, s00 + 1, 64);
            float v10 = __shfl(reg, s00 + 8, 64);
            float v11 = __shfl(reg, s00 + 9, 64);
            vl = (v00*(1.f-fxl) + v01*fxl)*(1.f-fyl) + (v10*(1.f-fxl) + v11*fxl)*fyl;
        } else if (lane < 49) {
            vl = bilin(iml, kxl + (float)(ci-3), kyl + (float)(rr-3));
        }
        // ---- right patch ----
        float frx = floorf(kxr), fry = floorf(kyr);
        int xbr = (int)frx - 3, ybr = (int)fry - 3;
        float fxr = kxr - frx, fyr = kyr - fry;
        float vr = 0.f;
        if (xbr >= 0 && xbr <= WW-8 && ybr >= 0 && ybr <= HH-8) {  // wave-uniform
            float reg = imr[(size_t)(ybr + reg_r) * WW + xbr + reg_c];
            float v00 = __shfl(reg, s00,     64);
            float v01 = __shfl(reg, s00 + 1, 64);
            float v10 = __shfl(reg, s00 + 8, 64);
            float v11 = __shfl(reg, s00 + 9, 64);
            vr = (v00*(1.f-fxr) + v01*fxr)*(1.f-fyr) + (v10*(1.f-fxr) + v11*fxr)*fyr;
        } else if (lane < 49) {
            vr = bilin(imr, kxr + (float)(ci-3), kyr + (float)(rr-3));
        }

        float adiff = (lane < 49) ? fabsf(vl - vr) : 0.f;
        float cl = __shfl(vl, 24, 64);   // center sample (3,3)
        float cr = __shfl(vr, 24, 64);
        #pragma unroll
        for (int off = 32; off > 0; off >>= 1) adiff += __shfl_down(adiff, off, 64);

        if (lane == 0) {
            float diff = adiff / 49.f;
            float isb  = (cl > 0.02f) ? 1.f : 0.f;   // BRIGHT
            float w    = sc * isb;
            float ydiff = fabsf(kyl - kyr);
            float dc = fabsf(cl - cr);
            float sl1 = (dc < 1.f) ? 0.5f * dc * dc : dc - 0.5f;

            const float* q = Q + b * 16;
            float dsp = kxl - kxr;
            float p0 = q[0]*kxl + q[1]*kyl + q[2]*dsp  + q[3];
            float p1 = q[4]*kxl + q[5]*kyl + q[6]*dsp  + q[7];
            float p2 = q[8]*kxl + q[9]*kyl + q[10]*dsp + q[11];
            float p3 = q[12]*kxl + q[13]*kyl + q[14]*dsp + q[15];
            float Wc = fmaxf(p3, 1e-6f);
            float X = p0 / Wc, Y = p1 / Wc, Z = p2 / Wc;
            bool valid = (Z > 100.f) && (Z < 30000.f) && (sc > 0.1f);
            float x  = X / 1000.f;
            float hh = Y / 1000.f;
            float y  = Z / 1000.f;
            float sq = x * x + y * y;
            if (!valid) { x = 0.f; y = 0.f; sq = 1e18f; }   // sentinel
            pts[pt] = make_float4(x, y, sq, hh);

            a0 += sc;  a1 += ydiff * sc;  a2 += ydiff;
            a3 += w;   a4 += diff * w;    a5 += sl1 * w;
            a6 += (sc > 0.1f) ? 1.f : 0.f;
        }
    }

    __shared__ float red[4][7];
    if (lane == 0) {
        red[wave][0]=a0; red[wave][1]=a1; red[wave][2]=a2; red[wave][3]=a3;
        red[wave][4]=a4; red[wave][5]=a5; red[wave][6]=a6;
    }
    __syncthreads();
    if (threadIdx.x < 8) {
        int k = threadIdx.x;
        float v = 0.f;
        if (k < 7) v = red[0][k] + red[1][k] + red[2][k] + red[3][k];
        partials[blockIdx.x * 8 + k] = v;
    }
}

// ---------------- Kernel B1: KNN scan over one m-segment --------------------
// grid (32, NSPLIT, BB); block = 4 waves; wave = 4 quads x 16 chunks; PPT=4.
// Each block: 64 points x 400 candidates; tile = 6.4 KB -> 8 blocks/CU, 8 w/SIMD.
__global__ __launch_bounds__(256) void knn_scan(
    const float4* __restrict__ pts, unsigned* __restrict__ keybuf)
{
    __shared__ float4 tile[MSEG];   // 6.4 KB
    int b = blockIdx.z, seg = blockIdx.y;
    int mseg0 = seg * MSEG;
    for (int i = threadIdx.x; i < MSEG; i += 256) tile[i] = pts[b * NN + mseg0 + i];
    __syncthreads();

    int lane = threadIdx.x & 63, wave = threadIdx.x >> 6;
    int qi = lane >> 4;           // quad in wave (0..3)
    int c  = lane & 15;           // chunk id (0..15)
    int n0 = blockIdx.x * 64 + (wave * 4 + qi) * PPT;

    unsigned K[PPT][5];
    float nx2[PPT], ny2[PPT], sqn[PPT];
    #pragma unroll
    for (int j = 0; j < PPT; ++j) {
        int n = n0 + j;
        float4 me = (n < NN) ? pts[b * NN + n] : make_float4(0.f, 0.f, 1e18f, 0.f);
        nx2[j] = -2.f * me.x; ny2[j] = -2.f * me.y; sqn[j] = me.z;
        #pragma unroll
        for (int t = 0; t < 5; ++t) K[j][t] = 0xFFFFFFFFu;
    }

    const int mb = c * CK2;       // local tile base; stride 100 words = 2-way banks (free)
    // self-index can only appear in the segment containing this block's points
    bool self_here = (blockIdx.x * 64 + 63 >= mseg0) && (blockIdx.x * 64 < mseg0 + MSEG);

    if (self_here) {
        #pragma unroll 5
        for (int mm = 0; mm < CK2; ++mm) {
            int ml = mb + mm, m = mseg0 + ml;
            float4 o = tile[ml];
            #pragma unroll
            for (int j = 0; j < PPT; ++j) {
                float t = fmaf(ny2[j], o.y, o.z);
                t = fmaf(nx2[j], o.x, t);
                float d2 = fmaxf(t + sqn[j], 1e-12f);
                unsigned u = (__float_as_uint(d2) & 0xFFFFF800u) | (unsigned)m;
                u = (m == n0 + j) ? 0xFFFFFFFFu : u;   // exclude self
                ins5(K[j], u);
            }
        }
    } else {
        #pragma unroll 5
        for (int mm = 0; mm < CK2; ++mm) {
            int ml = mb + mm, m = mseg0 + ml;
            float4 o = tile[ml];
            #pragma unroll
            for (int j = 0; j < PPT; ++j) {
                float t = fmaf(ny2[j], o.y, o.z);
                t = fmaf(nx2[j], o.x, t);
                float d2 = fmaxf(t + sqn[j], 1e-12f);
                unsigned u = (__float_as_uint(d2) & 0xFFFFF800u) | (unsigned)m;
                ins5(K[j], u);
            }
        }
    }

    // merge the 16 chunk lists of each quad (xor offsets stay in the 16-lane group)
    #pragma unroll
    for (int off = 1; off < 16; off <<= 1) {
        #pragma unroll
        for (int j = 0; j < PPT; ++j) {
            unsigned B0 = (unsigned)__shfl_xor((int)K[j][0], off, 64);
            unsigned B1 = (unsigned)__shfl_xor((int)K[j][1], off, 64);
            unsigned B2 = (unsigned)__shfl_xor((int)K[j][2], off, 64);
            unsigned B3 = (unsigned)__shfl_xor((int)K[j][3], off, 64);
            unsigned B4 = (unsigned)__shfl_xor((int)K[j][4], off, 64);
            ins5(K[j], B0); ins5(K[j], B1); ins5(K[j], B2); ins5(K[j], B3); ins5(K[j], B4);
        }
    }

    // write: lanes c=0..4 of each quad write rank j=c for the quad's 4 points (uint4)
    if (c < 5) {
        unsigned w0, w1, w2, w3;
        w0 = K[0][0]; w1 = K[1][0]; w2 = K[2][0]; w3 = K[3][0];
        if (c == 1) { w0 = K[0][1]; w1 = K[1][1]; w2 = K[2][1]; w3 = K[3][1]; }
        if (c == 2) { w0 = K[0][2]; w1 = K[1][2]; w2 = K[2][2]; w3 = K[3][2]; }
        if (c == 3) { w0 = K[0][3]; w1 = K[1][3]; w2 = K[2][3]; w3 = K[3][3]; }
        if (c == 4) { w0 = K[0][4]; w1 = K[1][4]; w2 = K[2][4]; w3 = K[3][4]; }
        uint4* dst = (uint4*)&keybuf[(size_t)(((b * NSPLIT + seg) * 5 + c)) * KSTRIDE + n0];
        *dst = make_uint4(w0, w1, w2, w3);
    }
}

// ---------------- Kernel B2: merge 25 partial keys/point + epilogue ---------
// grid (8, BB); one thread per point.
__global__ __launch_bounds__(256) void knn_merge(
    const float4* __restrict__ pts, const unsigned* __restrict__ keybuf,
    float* __restrict__ batch_acc)
{
    int b = blockIdx.y;
    int n = blockIdx.x * 256 + threadIdx.x;

    float ls = 0.f, pen = 0.f, hacc = 0.f, cnt = 0.f;
    if (n < NN) {
        float4 me = pts[b * NN + n];
        if (me.z < 1e17f) {
            unsigned K[5] = {0xFFFFFFFFu,0xFFFFFFFFu,0xFFFFFFFFu,0xFFFFFFFFu,0xFFFFFFFFu};
            #pragma unroll
            for (int s = 0; s < NSPLIT; ++s) {
                #pragma unroll
                for (int j = 0; j < 5; ++j) {
                    unsigned u = keybuf[(size_t)((b * NSPLIT + s) * 5 + j) * KSTRIDE + n];
                    ins5(K, u);
                }
            }
            float hsum = 0.f;
            #pragma unroll
            for (int t = 0; t < 5; ++t) {
                int idx = (int)(K[t] & 2047u);
                float4 o = pts[b * NN + idx];
                float dot = me.x * o.x + me.y * o.y;
                float d2 = (me.z + o.z) - 2.f * dot;        // exact recompute
                float nd = fmaxf(sqrtf(fmaxf(d2, 1e-12f)), 0.001f);
                hsum += o.w;
                pen  += fmaxf(fabsf(o.w - me.w) / nd - 0.4f, 0.f);
            }
            float lm = hsum / 5.f;
            float dd = fabsf(me.w - lm);
            ls = (dd < 0.01f) ? 0.5f * dd * dd / 0.01f : dd - 0.005f;  // smooth_l1 beta=0.01
            hacc = me.w;
            cnt  = 1.f;
        }
    }

    #pragma unroll
    for (int off = 32; off > 0; off >>= 1) {
        ls   += __shfl_down(ls,   off, 64);
        pen  += __shfl_down(pen,  off, 64);
        hacc += __shfl_down(hacc, off, 64);
        cnt  += __shfl_down(cnt,  off, 64);
    }
    __shared__ float r2[4][4];
    int wave = threadIdx.x >> 6, lane = threadIdx.x & 63;
    if (lane == 0) { r2[wave][0]=cnt; r2[wave][1]=ls; r2[wave][2]=pen; r2[wave][3]=hacc; }
    __syncthreads();
    if (threadIdx.x == 0) {
        float tc = r2[0][0]+r2[1][0]+r2[2][0]+r2[3][0];
        float tl = r2[0][1]+r2[1][1]+r2[2][1]+r2[3][1];
        float tp = r2[0][2]+r2[1][2]+r2[2][2]+r2[3][2];
        float th = r2[0][3]+r2[1][3]+r2[2][3]+r2[3][3];
        atomicAdd(&batch_acc[b * 4 + 0], tc);
        atomicAdd(&batch_acc[b * 4 + 1], tl);
        atomicAdd(&batch_acc[b * 4 + 2], tp);
        atomicAdd(&batch_acc[b * 4 + 3], th);
    }
}

// ---------------- Kernel C: final scalar epilogue ---------------------------
__global__ __launch_bounds__(256) void final_kernel(
    const float* __restrict__ partials, const float* __restrict__ batch_acc,
    float* __restrict__ out)
{
    float s[8] = {0,0,0,0,0,0,0,0};
    for (int r = threadIdx.x; r < PT_BLOCKS; r += 256) {
        #pragma unroll
        for (int k = 0; k < 8; ++k) s[k] += partials[r * 8 + k];
    }
    #pragma unroll
    for (int off = 32; off > 0; off >>= 1) {
        #pragma unroll
        for (int k = 0; k < 8; ++k) s[k] += __shfl_down(s[k], off, 64);
    }
    __shared__ float wsum_s[4][8];
    int wv = threadIdx.x >> 6, lane = threadIdx.x & 63;
    if (lane == 0) {
        #pragma unroll
        for (int k = 0; k < 8; ++k) wsum_s[wv][k] = s[k];
    }
    __syncthreads();
    if (threadIdx.x == 0) {
        float t[8];
        #pragma unroll
        for (int k = 0; k < 8; ++k)
            t[k] = wsum_s[0][k] + wsum_s[1][k] + wsum_s[2][k] + wsum_s[3][k];
        float ssc = t[0], yds = t[1], yd = t[2], wsum = t[3], dw = t[4], iw = t[5], cnts = t[6];

        float l_epi = (ssc > 1e-4f) ? yds / fmaxf(ssc, 1e-12f) : yd / (float)NPT;
        float safe = fmaxf(wsum, 1e-12f);
        float l_photo = (wsum > 1e-4f) ? (dw / safe + iw / safe) : 0.f;

        float als = 0.f, alsl = 0.f, alz = 0.f, okc = 0.f;
        for (int b = 0; b < BB; ++b) {
            float nvf  = batch_acc[b * 4 + 0];
            float lsb  = batch_acc[b * 4 + 1];
            float penb = batch_acc[b * 4 + 2];
            float hb   = batch_acc[b * 4 + 3];
            float nv = fmaxf(nvf, 1.f);
            float ok = (nvf >= 10.f) ? 1.f : 0.f;
            als  += ok * (lsb / nv);
            alsl += ok * (penb / (nv * 5.f));   // K = 5
            alz  += ok * fabsf(hb / nv);
            okc  += ok;
        }
        float nb = fmaxf(okc, 1.f);
        bool gate = (cnts >= 10.f) && (okc > 0.f);
        out[0] = l_photo;
        out[1] = l_epi;
        out[2] = gate ? als / nb : 0.f;
        out[3] = gate ? alsl / nb : 0.f;
        out[4] = gate ? alz / nb : 0.f;
    }
}

extern "C" void kernel_launch(void* const* d_in, const int* in_sizes, int n_in,
                              void* d_out, int out_size, void* d_ws, size_t ws_size,
                              hipStream_t stream)
{
    const float* lg     = (const float*)d_in[0];
    const float* rg     = (const float*)d_in[1];
    const float* kpl    = (const float*)d_in[2];
    const float* kpr    = (const float*)d_in[3];
    const float* scores = (const float*)d_in[4];
    const float* Q      = (const float*)d_in[5];
    float* out = (float*)d_out;

    char* ws = (char*)d_ws;
    float4*   pts       = (float4*)ws;                  // 512000 B
    float*    partials  = (float*)(ws + 512000);        // 1000*8*4 = 32000 B
    float*    batch_acc = (float*)(ws + 544000);        // 16*4*4 = 256 B
    unsigned* keybuf    = (unsigned*)(ws + 544256);     // 16*5*5*2048*4 = 3276800 B

    point_kernel<<<PT_BLOCKS, 256, 0, stream>>>(lg, rg, kpl, kpr, scores, Q,
                                                pts, partials, batch_acc);
    knn_scan<<<dim3(32, NSPLIT, BB), 256, 0, stream>>>(pts, keybuf);
    knn_merge<<<dim3(8, BB), 256, 0, stream>>>(pts, keybuf, batch_acc);
    final_kernel<<<1, 256, 0, stream>>>(partials, batch_acc, out);
}

// Round 7
// 204.871 us; speedup vs baseline: 1.4326x; 1.0274x over previous
//
#include <hip/hip_runtime.h>

#define BB 16
#define NN 2000
#define HH 720
#define WW 1280
#define NPT (BB*NN)           // 32000 keypoints
#define PT_BLOCKS (NPT/32)    // 1000 blocks, 4 waves x 8 points each
#define PPT 4                 // points per thread (knn scan)
#define NCHUNK 16             // chunk-lanes per point-quad
#define NSPLIT 5              // m-range splits
#define MSEG (NN/NSPLIT)      // 400 candidates per segment
#define CK2 (MSEG/NCHUNK)     // 25 m's per chunk-lane
#define KSTRIDE 2048          // keybuf point stride (>= 32*64)

static __device__ __forceinline__ unsigned u_min(unsigned a, unsigned b){ return a < b ? a : b; }

// median of 3 (unsigned) — single VOP3 v_med3_u32
static __device__ __forceinline__ unsigned u_med3(unsigned a, unsigned b, unsigned c) {
    unsigned d;
    asm("v_med3_u32 %0, %1, %2, %3" : "=v"(d) : "v"(a), "v"(b), "v"(c));
    return d;
}

// sorted top-5 insert (ascending uint keys).
// Invariant K0<=K1<=K2<=K3<=K4. Ki' = min(Ki, max(K(i-1), u)) == med3(K(i-1), Ki, u)
// under the invariant -> 1 v_min + 4 v_med3 = 5 VALU ops (was 9).
// Downward order uses pre-update (old) neighbors as required.
__device__ __forceinline__ void ins5(unsigned K[5], unsigned u) {
    K[4] = u_med3(K[3], K[4], u);
    K[3] = u_med3(K[2], K[3], u);
    K[2] = u_med3(K[1], K[2], u);
    K[1] = u_med3(K[0], K[1], u);
    K[0] = u_min(K[0], u);
}

// ---------------- bilinear sample, exact reference semantics (fallback) -----
__device__ __forceinline__ float bilin(const float* __restrict__ im, float px, float py) {
    px = fminf(fmaxf(px, 0.f), (float)(WW - 1));
    py = fminf(fmaxf(py, 0.f), (float)(HH - 1));
    float x0f = floorf(px), y0f = floorf(py);
    float fx = px - x0f, fy = py - y0f;
    int x0 = min(max((int)x0f, 0), WW - 1);
    int x1 = min(x0 + 1, WW - 1);
    int y0 = min(max((int)y0f, 0), HH - 1);
    int y1 = min(y0 + 1, HH - 1);
    const float* r0 = im + (size_t)y0 * WW;
    const float* r1 = im + (size_t)y1 * WW;
    float v00 = r0[x0], v01 = r0[x1], v10 = r1[x0], v11 = r1[x1];
    return (v00 * (1.f - fx) + v01 * fx) * (1.f - fy)
         + (v10 * (1.f - fx) + v11 * fx) * fy;
}

// ---------------- Kernel A: patch loss + projection (unchanged, passing) ----
__global__ __launch_bounds__(256) void point_kernel(
    const float* __restrict__ lg, const float* __restrict__ rg,
    const float* __restrict__ kpl, const float* __restrict__ kpr,
    const float* __restrict__ scores, const float* __restrict__ Q,
    float4* __restrict__ pts, float* __restrict__ partials,
    float* __restrict__ batch_acc)
{
    if (blockIdx.x == 0 && threadIdx.x < BB * 4) batch_acc[threadIdx.x] = 0.f;

    int wave = threadIdx.x >> 6, lane = threadIdx.x & 63;
    int rr = lane / 7, ci = lane - rr * 7;      // sample (row,col) for lane<49
    int s00 = lane + rr;                        // = rr*8+ci in 8x8 region
    if (s00 > 54) s00 = 54;                     // keep shfl idx valid for lanes>=49
    int reg_r = lane >> 3, reg_c = lane & 7;    // region-load position

    float a0=0.f,a1=0.f,a2=0.f,a3=0.f,a4=0.f,a5=0.f,a6=0.f;

    for (int it = 0; it < 8; ++it) {
        int pt = blockIdx.x * 32 + wave * 8 + it;
        int b = pt / NN;
        const float* iml = lg + (size_t)b * (HH * WW);
        const float* imr = rg + (size_t)b * (HH * WW);
        float kxl = kpl[2*pt], kyl = kpl[2*pt+1];
        float kxr = kpr[2*pt], kyr = kpr[2*pt+1];
        float sc  = scores[pt];

        // ---- left patch ----
        float flx = floorf(kxl), fly = floorf(kyl);
        int xbl = (int)flx - 3, ybl = (int)fly - 3;
        float fxl = kxl - flx, fyl = kyl - fly;
        float vl = 0.f;
        if (xbl >= 0 && xbl <= WW-8 && ybl >= 0 && ybl <= HH-8) {  // wave-uniform
            float reg = iml[(size_t)(ybl + reg_r) * WW + xbl + reg_c];
            float v00 = __shfl(reg, s00,     64);
            float v01 = __shfl(reg, s00 + 1, 64);
            float v10 = __shfl(reg, s00 + 8, 64);
            float v11 = __shfl(reg, s00 + 9, 64);
            vl = (v00*(1.f-fxl) + v01*fxl)*(1.f-fyl) + (v10*(1.f-fxl) + v11*fxl)*fyl;
        } else if (lane < 49) {
            vl = bilin(iml, kxl + (float)(ci-3), kyl + (float)(rr-3));
        }
        // ---- right patch ----
        float frx = floorf(kxr), fry = floorf(kyr);
        int xbr = (int)frx - 3, ybr = (int)fry - 3;
        float fxr = kxr - frx, fyr = kyr - fry;
        float vr = 0.f;
        if (xbr >= 0 && xbr <= WW-8 && ybr >= 0 && ybr <= HH-8) {  // wave-uniform
            float reg = imr[(size_t)(ybr + reg_r) * WW + xbr + reg_c];
            float v00 = __shfl(reg, s00,     64);
            float v01 = __shfl(reg, s00 + 1, 64);
            float v10 = __shfl(reg, s00 + 8, 64);
            float v11 = __shfl(reg, s00 + 9, 64);
            vr = (v00*(1.f-fxr) + v01*fxr)*(1.f-fyr) + (v10*(1.f-fxr) + v11*fxr)*fyr;
        } else if (lane < 49) {
            vr = bilin(imr, kxr + (float)(ci-3), kyr + (float)(rr-3));
        }

        float adiff = (lane < 49) ? fabsf(vl - vr) : 0.f;
        float cl = __shfl(vl, 24, 64);   // center sample (3,3)
        float cr = __shfl(vr, 24, 64);
        #pragma unroll
        for (int off = 32; off > 0; off >>= 1) adiff += __shfl_down(adiff, off, 64);

        if (lane == 0) {
            float diff = adiff / 49.f;
            float isb  = (cl > 0.02f) ? 1.f : 0.f;   // BRIGHT
            float w    = sc * isb;
            float ydiff = fabsf(kyl - kyr);
            float dc = fabsf(cl - cr);
            float sl1 = (dc < 1.f) ? 0.5f * dc * dc : dc - 0.5f;

            const float* q = Q + b * 16;
            float dsp = kxl - kxr;
            float p0 = q[0]*kxl + q[1]*kyl + q[2]*dsp  + q[3];
            float p1 = q[4]*kxl + q[5]*kyl + q[6]*dsp  + q[7];
            float p2 = q[8]*kxl + q[9]*kyl + q[10]*dsp + q[11];
            float p3 = q[12]*kxl + q[13]*kyl + q[14]*dsp + q[15];
            float Wc = fmaxf(p3, 1e-6f);
            float X = p0 / Wc, Y = p1 / Wc, Z = p2 / Wc;
            bool valid = (Z > 100.f) && (Z < 30000.f) && (sc > 0.1f);
            float x  = X / 1000.f;
            float hh = Y / 1000.f;
            float y  = Z / 1000.f;
            float sq = x * x + y * y;
            if (!valid) { x = 0.f; y = 0.f; sq = 1e18f; }   // sentinel
            pts[pt] = make_float4(x, y, sq, hh);

            a0 += sc;  a1 += ydiff * sc;  a2 += ydiff;
            a3 += w;   a4 += diff * w;    a5 += sl1 * w;
            a6 += (sc > 0.1f) ? 1.f : 0.f;
        }
    }

    __shared__ float red[4][7];
    if (lane == 0) {
        red[wave][0]=a0; red[wave][1]=a1; red[wave][2]=a2; red[wave][3]=a3;
        red[wave][4]=a4; red[wave][5]=a5; red[wave][6]=a6;
    }
    __syncthreads();
    if (threadIdx.x < 8) {
        int k = threadIdx.x;
        float v = 0.f;
        if (k < 7) v = red[0][k] + red[1][k] + red[2][k] + red[3][k];
        partials[blockIdx.x * 8 + k] = v;
    }
}

// ---------------- Kernel B1: KNN scan over one m-segment --------------------
// grid (32, NSPLIT, BB); block = 4 waves; wave = 4 quads x 16 chunks; PPT=4.
__global__ __launch_bounds__(256) void knn_scan(
    const float4* __restrict__ pts, unsigned* __restrict__ keybuf)
{
    __shared__ float4 tile[MSEG];   // 6.4 KB
    int b = blockIdx.z, seg = blockIdx.y;
    int mseg0 = seg * MSEG;
    for (int i = threadIdx.x; i < MSEG; i += 256) tile[i] = pts[b * NN + mseg0 + i];
    __syncthreads();

    int lane = threadIdx.x & 63, wave = threadIdx.x >> 6;
    int qi = lane >> 4;           // quad in wave (0..3)
    int c  = lane & 15;           // chunk id (0..15)
    int n0 = blockIdx.x * 64 + (wave * 4 + qi) * PPT;

    unsigned K[PPT][5];
    float nx2[PPT], ny2[PPT], sqn[PPT];
    #pragma unroll
    for (int j = 0; j < PPT; ++j) {
        int n = n0 + j;
        float4 me = (n < NN) ? pts[b * NN + n] : make_float4(0.f, 0.f, 1e18f, 0.f);
        nx2[j] = -2.f * me.x; ny2[j] = -2.f * me.y; sqn[j] = me.z;
        #pragma unroll
        for (int t = 0; t < 5; ++t) K[j][t] = 0xFFFFFFFFu;
    }

    const int mb = c * CK2;       // local tile base; stride 100 words = 2-way banks (free)
    bool self_here = (blockIdx.x * 64 + 63 >= mseg0) && (blockIdx.x * 64 < mseg0 + MSEG);

    if (self_here) {
        #pragma unroll 5
        for (int mm = 0; mm < CK2; ++mm) {
            int ml = mb + mm, m = mseg0 + ml;
            float4 o = tile[ml];
            #pragma unroll
            for (int j = 0; j < PPT; ++j) {
                float t = fmaf(ny2[j], o.y, o.z);
                t = fmaf(nx2[j], o.x, t);
                float d2 = fmaxf(t + sqn[j], 1e-12f);
                unsigned u = (__float_as_uint(d2) & 0xFFFFF800u) | (unsigned)m;
                u = (m == n0 + j) ? 0xFFFFFFFFu : u;   // exclude self
                ins5(K[j], u);
            }
        }
    } else {
        #pragma unroll 5
        for (int mm = 0; mm < CK2; ++mm) {
            int ml = mb + mm, m = mseg0 + ml;
            float4 o = tile[ml];
            #pragma unroll
            for (int j = 0; j < PPT; ++j) {
                float t = fmaf(ny2[j], o.y, o.z);
                t = fmaf(nx2[j], o.x, t);
                float d2 = fmaxf(t + sqn[j], 1e-12f);
                unsigned u = (__float_as_uint(d2) & 0xFFFFF800u) | (unsigned)m;
                ins5(K[j], u);
            }
        }
    }

    // merge the 16 chunk lists of each quad (xor offsets stay in the 16-lane group)
    #pragma unroll
    for (int off = 1; off < 16; off <<= 1) {
        #pragma unroll
        for (int j = 0; j < PPT; ++j) {
            unsigned B0 = (unsigned)__shfl_xor((int)K[j][0], off, 64);
            unsigned B1 = (unsigned)__shfl_xor((int)K[j][1], off, 64);
            unsigned B2 = (unsigned)__shfl_xor((int)K[j][2], off, 64);
            unsigned B3 = (unsigned)__shfl_xor((int)K[j][3], off, 64);
            unsigned B4 = (unsigned)__shfl_xor((int)K[j][4], off, 64);
            ins5(K[j], B0); ins5(K[j], B1); ins5(K[j], B2); ins5(K[j], B3); ins5(K[j], B4);
        }
    }

    // write: lanes c=0..4 of each quad write rank j=c for the quad's 4 points (uint4)
    if (c < 5) {
        unsigned w0, w1, w2, w3;
        w0 = K[0][0]; w1 = K[1][0]; w2 = K[2][0]; w3 = K[3][0];
        if (c == 1) { w0 = K[0][1]; w1 = K[1][1]; w2 = K[2][1]; w3 = K[3][1]; }
        if (c == 2) { w0 = K[0][2]; w1 = K[1][2]; w2 = K[2][2]; w3 = K[3][2]; }
        if (c == 3) { w0 = K[0][3]; w1 = K[1][3]; w2 = K[2][3]; w3 = K[3][3]; }
        if (c == 4) { w0 = K[0][4]; w1 = K[1][4]; w2 = K[2][4]; w3 = K[3][4]; }
        uint4* dst = (uint4*)&keybuf[(size_t)(((b * NSPLIT + seg) * 5 + c)) * KSTRIDE + n0];
        *dst = make_uint4(w0, w1, w2, w3);
    }
}

// ---------------- Kernel B2: merge 25 partial keys/point + epilogue ---------
// grid (8, BB); one thread per point.
__global__ __launch_bounds__(256) void knn_merge(
    const float4* __restrict__ pts, const unsigned* __restrict__ keybuf,
    float* __restrict__ batch_acc)
{
    int b = blockIdx.y;
    int n = blockIdx.x * 256 + threadIdx.x;

    float ls = 0.f, pen = 0.f, hacc = 0.f, cnt = 0.f;
    if (n < NN) {
        float4 me = pts[b * NN + n];
        if (me.z < 1e17f) {
            unsigned K[5] = {0xFFFFFFFFu,0xFFFFFFFFu,0xFFFFFFFFu,0xFFFFFFFFu,0xFFFFFFFFu};
            #pragma unroll
            for (int s = 0; s < NSPLIT; ++s) {
                #pragma unroll
                for (int j = 0; j < 5; ++j) {
                    unsigned u = keybuf[(size_t)((b * NSPLIT + s) * 5 + j) * KSTRIDE + n];
                    ins5(K, u);
                }
            }
            float hsum = 0.f;
            #pragma unroll
            for (int t = 0; t < 5; ++t) {
                int idx = (int)(K[t] & 2047u);
                float4 o = pts[b * NN + idx];
                float dot = me.x * o.x + me.y * o.y;
                float d2 = (me.z + o.z) - 2.f * dot;        // exact recompute
                float nd = fmaxf(sqrtf(fmaxf(d2, 1e-12f)), 0.001f);
                hsum += o.w;
                pen  += fmaxf(fabsf(o.w - me.w) / nd - 0.4f, 0.f);
            }
            float lm = hsum / 5.f;
            float dd = fabsf(me.w - lm);
            ls = (dd < 0.01f) ? 0.5f * dd * dd / 0.01f : dd - 0.005f;  // smooth_l1 beta=0.01
            hacc = me.w;
            cnt  = 1.f;
        }
    }

    #pragma unroll
    for (int off = 32; off > 0; off >>= 1) {
        ls   += __shfl_down(ls,   off, 64);
        pen  += __shfl_down(pen,  off, 64);
        hacc += __shfl_down(hacc, off, 64);
        cnt  += __shfl_down(cnt,  off, 64);
    }
    __shared__ float r2[4][4];
    int wave = threadIdx.x >> 6, lane = threadIdx.x & 63;
    if (lane == 0) { r2[wave][0]=cnt; r2[wave][1]=ls; r2[wave][2]=pen; r2[wave][3]=hacc; }
    __syncthreads();
    if (threadIdx.x == 0) {
        float tc = r2[0][0]+r2[1][0]+r2[2][0]+r2[3][0];
        float tl = r2[0][1]+r2[1][1]+r2[2][1]+r2[3][1];
        float tp = r2[0][2]+r2[1][2]+r2[2][2]+r2[3][2];
        float th = r2[0][3]+r2[1][3]+r2[2][3]+r2[3][3];
        atomicAdd(&batch_acc[b * 4 + 0], tc);
        atomicAdd(&batch_acc[b * 4 + 1], tl);
        atomicAdd(&batch_acc[b * 4 + 2], tp);
        atomicAdd(&batch_acc[b * 4 + 3], th);
    }
}

// ---------------- Kernel C: final scalar epilogue ---------------------------
__global__ __launch_bounds__(256) void final_kernel(
    const float* __restrict__ partials, const float* __restrict__ batch_acc,
    float* __restrict__ out)
{
    float s[8] = {0,0,0,0,0,0,0,0};
    for (int r = threadIdx.x; r < PT_BLOCKS; r += 256) {
        #pragma unroll
        for (int k = 0; k < 8; ++k) s[k] += partials[r * 8 + k];
    }
    #pragma unroll
    for (int off = 32; off > 0; off >>= 1) {
        #pragma unroll
        for (int k = 0; k < 8; ++k) s[k] += __shfl_down(s[k], off, 64);
    }
    __shared__ float wsum_s[4][8];
    int wv = threadIdx.x >> 6, lane = threadIdx.x & 63;
    if (lane == 0) {
        #pragma unroll
        for (int k = 0; k < 8; ++k) wsum_s[wv][k] = s[k];
    }
    __syncthreads();
    if (threadIdx.x == 0) {
        float t[8];
        #pragma unroll
        for (int k = 0; k < 8; ++k)
            t[k] = wsum_s[0][k] + wsum_s[1][k] + wsum_s[2][k] + wsum_s[3][k];
        float ssc = t[0], yds = t[1], yd = t[2], wsum = t[3], dw = t[4], iw = t[5], cnts = t[6];

        float l_epi = (ssc > 1e-4f) ? yds / fmaxf(ssc, 1e-12f) : yd / (float)NPT;
        float safe = fmaxf(wsum, 1e-12f);
        float l_photo = (wsum > 1e-4f) ? (dw / safe + iw / safe) : 0.f;

        float als = 0.f, alsl = 0.f, alz = 0.f, okc = 0.f;
        for (int b = 0; b < BB; ++b) {
            float nvf  = batch_acc[b * 4 + 0];
            float lsb  = batch_acc[b * 4 + 1];
            float penb = batch_acc[b * 4 + 2];
            float hb   = batch_acc[b * 4 + 3];
            float nv = fmaxf(nvf, 1.f);
            float ok = (nvf >= 10.f) ? 1.f : 0.f;
            als  += ok * (lsb / nv);
            alsl += ok * (penb / (nv * 5.f));   // K = 5
            alz  += ok * fabsf(hb / nv);
            okc  += ok;
        }
        float nb = fmaxf(okc, 1.f);
        bool gate = (cnts >= 10.f) && (okc > 0.f);
        out[0] = l_photo;
        out[1] = l_epi;
        out[2] = gate ? als / nb : 0.f;
        out[3] = gate ? alsl / nb : 0.f;
        out[4] = gate ? alz / nb : 0.f;
    }
}

extern "C" void kernel_launch(void* const* d_in, const int* in_sizes, int n_in,
                              void* d_out, int out_size, void* d_ws, size_t ws_size,
                              hipStream_t stream)
{
    const float* lg     = (const float*)d_in[0];
    const float* rg     = (const float*)d_in[1];
    const float* kpl    = (const float*)d_in[2];
    const float* kpr    = (const float*)d_in[3];
    const float* scores = (const float*)d_in[4];
    const float* Q      = (const float*)d_in[5];
    float* out = (float*)d_out;

    char* ws = (char*)d_ws;
    float4*   pts       = (float4*)ws;                  // 512000 B
    float*    partials  = (float*)(ws + 512000);        // 1000*8*4 = 32000 B
    float*    batch_acc = (float*)(ws + 544000);        // 16*4*4 = 256 B
    unsigned* keybuf    = (unsigned*)(ws + 544256);     // 16*5*5*2048*4 = 3276800 B

    point_kernel<<<PT_BLOCKS, 256, 0, stream>>>(lg, rg, kpl, kpr, scores, Q,
                                                pts, partials, batch_acc);
    knn_scan<<<dim3(32, NSPLIT, BB), 256, 0, stream>>>(pts, keybuf);
    knn_merge<<<dim3(8, BB), 256, 0, stream>>>(pts, keybuf, batch_acc);
    final_kernel<<<1, 256, 0, stream>>>(partials, batch_acc, out);
}

// Round 8
// 190.540 us; speedup vs baseline: 1.5404x; 1.0752x over previous
//
#include <hip/hip_runtime.h>

#define BB 16
#define NN 2000
#define HH 720
#define WW 1280
#define NPT (BB*NN)           // 32000 keypoints
#define PT_BLOCKS (NPT/32)    // 1000 blocks, 4 waves x 8 points each
#define KSTRIDE 2048          // keybuf point stride

static __device__ __forceinline__ unsigned u_min(unsigned a, unsigned b){ return a < b ? a : b; }

// median of 3 (unsigned) — single VOP3 v_med3_u32
static __device__ __forceinline__ unsigned u_med3(unsigned a, unsigned b, unsigned c) {
    unsigned d;
    asm("v_med3_u32 %0, %1, %2, %3" : "=v"(d) : "v"(a), "v"(b), "v"(c));
    return d;
}

// sorted top-5 insert (ascending uint keys): 1 v_min + 4 v_med3 = 5 VALU ops.
// Invariant K0<=..<=K4; Ki' = med3(K(i-1), Ki, u) under the invariant.
__device__ __forceinline__ void ins5(unsigned K[5], unsigned u) {
    K[4] = u_med3(K[3], K[4], u);
    K[3] = u_med3(K[2], K[3], u);
    K[2] = u_med3(K[1], K[2], u);
    K[1] = u_med3(K[0], K[1], u);
    K[0] = u_min(K[0], u);
}

// ---------------- bilinear sample, exact reference semantics (fallback) -----
__device__ __forceinline__ float bilin(const float* __restrict__ im, float px, float py) {
    px = fminf(fmaxf(px, 0.f), (float)(WW - 1));
    py = fminf(fmaxf(py, 0.f), (float)(HH - 1));
    float x0f = floorf(px), y0f = floorf(py);
    float fx = px - x0f, fy = py - y0f;
    int x0 = min(max((int)x0f, 0), WW - 1);
    int x1 = min(x0 + 1, WW - 1);
    int y0 = min(max((int)y0f, 0), HH - 1);
    int y1 = min(y0 + 1, HH - 1);
    const float* r0 = im + (size_t)y0 * WW;
    const float* r1 = im + (size_t)y1 * WW;
    float v00 = r0[x0], v01 = r0[x1], v10 = r1[x0], v11 = r1[x1];
    return (v00 * (1.f - fx) + v01 * fx) * (1.f - fy)
         + (v10 * (1.f - fx) + v11 * fx) * fy;
}

// ---------------- Kernel A: patch loss + projection (unchanged, passing) ----
__global__ __launch_bounds__(256) void point_kernel(
    const float* __restrict__ lg, const float* __restrict__ rg,
    const float* __restrict__ kpl, const float* __restrict__ kpr,
    const float* __restrict__ scores, const float* __restrict__ Q,
    float4* __restrict__ pts, float* __restrict__ partials,
    float* __restrict__ batch_acc)
{
    if (blockIdx.x == 0 && threadIdx.x < BB * 4) batch_acc[threadIdx.x] = 0.f;

    int wave = threadIdx.x >> 6, lane = threadIdx.x & 63;
    int rr = lane / 7, ci = lane - rr * 7;      // sample (row,col) for lane<49
    int s00 = lane + rr;                        // = rr*8+ci in 8x8 region
    if (s00 > 54) s00 = 54;                     // keep shfl idx valid for lanes>=49
    int reg_r = lane >> 3, reg_c = lane & 7;    // region-load position

    float a0=0.f,a1=0.f,a2=0.f,a3=0.f,a4=0.f,a5=0.f,a6=0.f;

    for (int it = 0; it < 8; ++it) {
        int pt = blockIdx.x * 32 + wave * 8 + it;
        int b = pt / NN;
        const float* iml = lg + (size_t)b * (HH * WW);
        const float* imr = rg + (size_t)b * (HH * WW);
        float kxl = kpl[2*pt], kyl = kpl[2*pt+1];
        float kxr = kpr[2*pt], kyr = kpr[2*pt+1];
        float sc  = scores[pt];

        // ---- left patch ----
        float flx = floorf(kxl), fly = floorf(kyl);
        int xbl = (int)flx - 3, ybl = (int)fly - 3;
        float fxl = kxl - flx, fyl = kyl - fly;
        float vl = 0.f;
        if (xbl >= 0 && xbl <= WW-8 && ybl >= 0 && ybl <= HH-8) {  // wave-uniform
            float reg = iml[(size_t)(ybl + reg_r) * WW + xbl + reg_c];
            float v00 = __shfl(reg, s00,     64);
            float v01 = __shfl(reg, s00 + 1, 64);
            float v10 = __shfl(reg, s00 + 8, 64);
            float v11 = __shfl(reg, s00 + 9, 64);
            vl = (v00*(1.f-fxl) + v01*fxl)*(1.f-fyl) + (v10*(1.f-fxl) + v11*fxl)*fyl;
        } else if (lane < 49) {
            vl = bilin(iml, kxl + (float)(ci-3), kyl + (float)(rr-3));
        }
        // ---- right patch ----
        float frx = floorf(kxr), fry = floorf(kyr);
        int xbr = (int)frx - 3, ybr = (int)fry - 3;
        float fxr = kxr - frx, fyr = kyr - fry;
        float vr = 0.f;
        if (xbr >= 0 && xbr <= WW-8 && ybr >= 0 && ybr <= HH-8) {  // wave-uniform
            float reg = imr[(size_t)(ybr + reg_r) * WW + xbr + reg_c];
            float v00 = __shfl(reg, s00,     64);
            float v01 = __shfl(reg, s00 + 1, 64);
            float v10 = __shfl(reg, s00 + 8, 64);
            float v11 = __shfl(reg, s00 + 9, 64);
            vr = (v00*(1.f-fxr) + v01*fxr)*(1.f-fyr) + (v10*(1.f-fxr) + v11*fxr)*fyr;
        } else if (lane < 49) {
            vr = bilin(imr, kxr + (float)(ci-3), kyr + (float)(rr-3));
        }

        float adiff = (lane < 49) ? fabsf(vl - vr) : 0.f;
        float cl = __shfl(vl, 24, 64);   // center sample (3,3)
        float cr = __shfl(vr, 24, 64);
        #pragma unroll
        for (int off = 32; off > 0; off >>= 1) adiff += __shfl_down(adiff, off, 64);

        if (lane == 0) {
            float diff = adiff / 49.f;
            float isb  = (cl > 0.02f) ? 1.f : 0.f;   // BRIGHT
            float w    = sc * isb;
            float ydiff = fabsf(kyl - kyr);
            float dc = fabsf(cl - cr);
            float sl1 = (dc < 1.f) ? 0.5f * dc * dc : dc - 0.5f;

            const float* q = Q + b * 16;
            float dsp = kxl - kxr;
            float p0 = q[0]*kxl + q[1]*kyl + q[2]*dsp  + q[3];
            float p1 = q[4]*kxl + q[5]*kyl + q[6]*dsp  + q[7];
            float p2 = q[8]*kxl + q[9]*kyl + q[10]*dsp + q[11];
            float p3 = q[12]*kxl + q[13]*kyl + q[14]*dsp + q[15];
            float Wc = fmaxf(p3, 1e-6f);
            float X = p0 / Wc, Y = p1 / Wc, Z = p2 / Wc;
            bool valid = (Z > 100.f) && (Z < 30000.f) && (sc > 0.1f);
            float x  = X / 1000.f;
            float hh = Y / 1000.f;
            float y  = Z / 1000.f;
            float sq = x * x + y * y;
            if (!valid) { x = 0.f; y = 0.f; sq = 1e18f; }   // sentinel
            pts[pt] = make_float4(x, y, sq, hh);

            a0 += sc;  a1 += ydiff * sc;  a2 += ydiff;
            a3 += w;   a4 += diff * w;    a5 += sl1 * w;
            a6 += (sc > 0.1f) ? 1.f : 0.f;
        }
    }

    __shared__ float red[4][7];
    if (lane == 0) {
        red[wave][0]=a0; red[wave][1]=a1; red[wave][2]=a2; red[wave][3]=a3;
        red[wave][4]=a4; red[wave][5]=a5; red[wave][6]=a6;
    }
    __syncthreads();
    if (threadIdx.x < 8) {
        int k = threadIdx.x;
        float v = 0.f;
        if (k < 7) v = red[0][k] + red[1][k] + red[2][k] + red[3][k];
        partials[blockIdx.x * 8 + k] = v;
    }
}

// ---------------- Kernel B1: KNN scan — scalar candidate sweep, no LDS ------
// grid (8, ns, BB), block 256. Lane owns ONE point; all lanes sweep the
// segment's candidates via a wave-uniform loop (compiler emits s_load for
// pts[cand] since the index is uniform). No LDS, no merge shuffles.
__global__ __launch_bounds__(256) void knn_scan(
    const float4* __restrict__ pts, unsigned* __restrict__ keybuf,
    int msegLen, int ns)
{
    int b = blockIdx.z, seg = blockIdx.y;
    int mseg0 = seg * msegLen;
    int n = blockIdx.x * 256 + threadIdx.x;
    int nc = (n < NN) ? n : (NN - 1);          // clamp for safe loads

    float4 me = pts[b * NN + nc];
    float nx2 = -2.f * me.x, ny2 = -2.f * me.y, sqn = me.z;

    unsigned K[5] = {0xFFFFFFFFu,0xFFFFFFFFu,0xFFFFFFFFu,0xFFFFFFFFu,0xFFFFFFFFu};

    const float4* cand = pts + b * NN + mseg0;
    int nb0 = blockIdx.x * 256;
    bool has_self = (mseg0 < nb0 + 256) && (mseg0 + msegLen > nb0);  // block-uniform

    if (has_self) {
        #pragma unroll 5
        for (int mm = 0; mm < msegLen; ++mm) {
            float4 o = cand[mm];               // wave-uniform -> scalar load
            int m = mseg0 + mm;
            float t = fmaf(ny2, o.y, o.z);
            t = fmaf(nx2, o.x, t);
            float d2 = fmaxf(t + sqn, 1e-12f);
            unsigned u = (__float_as_uint(d2) & 0xFFFFF800u) | (unsigned)m;
            u = (m == n) ? 0xFFFFFFFFu : u;    // exclude self (2 ops, rare blocks)
            ins5(K, u);
        }
    } else {
        #pragma unroll 5
        for (int mm = 0; mm < msegLen; ++mm) {
            float4 o = cand[mm];               // wave-uniform -> scalar load
            int m = mseg0 + mm;
            float t = fmaf(ny2, o.y, o.z);
            t = fmaf(nx2, o.x, t);
            float d2 = fmaxf(t + sqn, 1e-12f);
            unsigned u = (__float_as_uint(d2) & 0xFFFFF800u) | (unsigned)m;
            ins5(K, u);
        }
    }

    if (n < NN) {
        size_t base = (size_t)((b * ns + seg) * 5) * KSTRIDE + n;
        keybuf[base              ] = K[0];
        keybuf[base + KSTRIDE    ] = K[1];
        keybuf[base + KSTRIDE * 2] = K[2];
        keybuf[base + KSTRIDE * 3] = K[3];
        keybuf[base + KSTRIDE * 4] = K[4];
    }
}

// ---------------- Kernel B2: merge 5*ns partial keys/point + epilogue -------
// grid (8, BB); one thread per point. Rank-rows are coalesced over n.
__global__ __launch_bounds__(256) void knn_merge(
    const float4* __restrict__ pts, const unsigned* __restrict__ keybuf,
    float* __restrict__ batch_acc, int ns)
{
    int b = blockIdx.y;
    int n = blockIdx.x * 256 + threadIdx.x;

    float ls = 0.f, pen = 0.f, hacc = 0.f, cnt = 0.f;
    if (n < NN) {
        float4 me = pts[b * NN + n];
        if (me.z < 1e17f) {
            unsigned K[5] = {0xFFFFFFFFu,0xFFFFFFFFu,0xFFFFFFFFu,0xFFFFFFFFu,0xFFFFFFFFu};
            for (int s = 0; s < ns; ++s) {
                #pragma unroll
                for (int j = 0; j < 5; ++j) {
                    unsigned u = keybuf[(size_t)((b * ns + s) * 5 + j) * KSTRIDE + n];
                    ins5(K, u);
                }
            }
            float hsum = 0.f;
            #pragma unroll
            for (int t = 0; t < 5; ++t) {
                int idx = (int)(K[t] & 2047u);
                float4 o = pts[b * NN + idx];
                float dot = me.x * o.x + me.y * o.y;
                float d2 = (me.z + o.z) - 2.f * dot;        // exact recompute
                float nd = fmaxf(sqrtf(fmaxf(d2, 1e-12f)), 0.001f);
                hsum += o.w;
                pen  += fmaxf(fabsf(o.w - me.w) / nd - 0.4f, 0.f);
            }
            float lm = hsum / 5.f;
            float dd = fabsf(me.w - lm);
            ls = (dd < 0.01f) ? 0.5f * dd * dd / 0.01f : dd - 0.005f;  // smooth_l1 beta=0.01
            hacc = me.w;
            cnt  = 1.f;
        }
    }

    #pragma unroll
    for (int off = 32; off > 0; off >>= 1) {
        ls   += __shfl_down(ls,   off, 64);
        pen  += __shfl_down(pen,  off, 64);
        hacc += __shfl_down(hacc, off, 64);
        cnt  += __shfl_down(cnt,  off, 64);
    }
    __shared__ float r2[4][4];
    int wave = threadIdx.x >> 6, lane = threadIdx.x & 63;
    if (lane == 0) { r2[wave][0]=cnt; r2[wave][1]=ls; r2[wave][2]=pen; r2[wave][3]=hacc; }
    __syncthreads();
    if (threadIdx.x == 0) {
        float tc = r2[0][0]+r2[1][0]+r2[2][0]+r2[3][0];
        float tl = r2[0][1]+r2[1][1]+r2[2][1]+r2[3][1];
        float tp = r2[0][2]+r2[1][2]+r2[2][2]+r2[3][2];
        float th = r2[0][3]+r2[1][3]+r2[2][3]+r2[3][3];
        atomicAdd(&batch_acc[b * 4 + 0], tc);
        atomicAdd(&batch_acc[b * 4 + 1], tl);
        atomicAdd(&batch_acc[b * 4 + 2], tp);
        atomicAdd(&batch_acc[b * 4 + 3], th);
    }
}

// ---------------- Kernel C: final scalar epilogue ---------------------------
__global__ __launch_bounds__(256) void final_kernel(
    const float* __restrict__ partials, const float* __restrict__ batch_acc,
    float* __restrict__ out)
{
    float s[8] = {0,0,0,0,0,0,0,0};
    for (int r = threadIdx.x; r < PT_BLOCKS; r += 256) {
        #pragma unroll
        for (int k = 0; k < 8; ++k) s[k] += partials[r * 8 + k];
    }
    #pragma unroll
    for (int off = 32; off > 0; off >>= 1) {
        #pragma unroll
        for (int k = 0; k < 8; ++k) s[k] += __shfl_down(s[k], off, 64);
    }
    __shared__ float wsum_s[4][8];
    int wv = threadIdx.x >> 6, lane = threadIdx.x & 63;
    if (lane == 0) {
        #pragma unroll
        for (int k = 0; k < 8; ++k) wsum_s[wv][k] = s[k];
    }
    __syncthreads();
    if (threadIdx.x == 0) {
        float t[8];
        #pragma unroll
        for (int k = 0; k < 8; ++k)
            t[k] = wsum_s[0][k] + wsum_s[1][k] + wsum_s[2][k] + wsum_s[3][k];
        float ssc = t[0], yds = t[1], yd = t[2], wsum = t[3], dw = t[4], iw = t[5], cnts = t[6];

        float l_epi = (ssc > 1e-4f) ? yds / fmaxf(ssc, 1e-12f) : yd / (float)NPT;
        float safe = fmaxf(wsum, 1e-12f);
        float l_photo = (wsum > 1e-4f) ? (dw / safe + iw / safe) : 0.f;

        float als = 0.f, alsl = 0.f, alz = 0.f, okc = 0.f;
        for (int b = 0; b < BB; ++b) {
            float nvf  = batch_acc[b * 4 + 0];
            float lsb  = batch_acc[b * 4 + 1];
            float penb = batch_acc[b * 4 + 2];
            float hb   = batch_acc[b * 4 + 3];
            float nv = fmaxf(nvf, 1.f);
            float ok = (nvf >= 10.f) ? 1.f : 0.f;
            als  += ok * (lsb / nv);
            alsl += ok * (penb / (nv * 5.f));   // K = 5
            alz  += ok * fabsf(hb / nv);
            okc  += ok;
        }
        float nb = fmaxf(okc, 1.f);
        bool gate = (cnts >= 10.f) && (okc > 0.f);
        out[0] = l_photo;
        out[1] = l_epi;
        out[2] = gate ? als / nb : 0.f;
        out[3] = gate ? alsl / nb : 0.f;
        out[4] = gate ? alz / nb : 0.f;
    }
}

extern "C" void kernel_launch(void* const* d_in, const int* in_sizes, int n_in,
                              void* d_out, int out_size, void* d_ws, size_t ws_size,
                              hipStream_t stream)
{
    const float* lg     = (const float*)d_in[0];
    const float* rg     = (const float*)d_in[1];
    const float* kpl    = (const float*)d_in[2];
    const float* kpr    = (const float*)d_in[3];
    const float* scores = (const float*)d_in[4];
    const float* Q      = (const float*)d_in[5];
    float* out = (float*)d_out;

    char* ws = (char*)d_ws;
    float4*   pts       = (float4*)ws;                  // 512000 B
    float*    partials  = (float*)(ws + 512000);        // 1000*8*4 = 32000 B
    float*    batch_acc = (float*)(ws + 544000);        // 16*4*4 = 256 B
    unsigned* keybuf    = (unsigned*)(ws + 544256);

    // pick largest NSPLIT whose keybuf fits ws (deterministic: ws_size constant)
    int ns = 16;
    size_t need = 544256 + (size_t)BB * 16 * 5 * KSTRIDE * 4;   // 11.0 MB
    if (ws_size < need) ns = 8;
    if (ws_size < 544256 + (size_t)BB * 8 * 5 * KSTRIDE * 4) ns = 4;
    int msegLen = NN / ns;

    point_kernel<<<PT_BLOCKS, 256, 0, stream>>>(lg, rg, kpl, kpr, scores, Q,
                                                pts, partials, batch_acc);
    knn_scan<<<dim3(8, ns, BB), 256, 0, stream>>>(pts, keybuf, msegLen, ns);
    knn_merge<<<dim3(8, BB), 256, 0, stream>>>(pts, keybuf, batch_acc, ns);
    final_kernel<<<1, 256, 0, stream>>>(partials, batch_acc, out);
}